// Round 1
// baseline (1252.899 us; speedup 1.0000x reference)
//
#include <hip/hip_runtime.h>
#include <math.h>

// Problem constants (validated at launch from in_sizes)
#define IN_DIM 16
#define HDIM   128
#define HEADS  4
#define HH     512   // HEADS*HDIM
#define FFH    256   // 2*HDIM
#define NEG_SLOPE 0.2f

// ---------------------------------------------------------------------------
// Preprocess: degree + edge_attr sums (for self-loop fill_value='mean')
// ---------------------------------------------------------------------------
__global__ void deg_kernel(const int* __restrict__ ei, const float* __restrict__ eattr,
                           float* deg, float* asum, int E) {
    int e = blockIdx.x * blockDim.x + threadIdx.x;
    if (e >= E) return;
    int d = ei[E + e];               // dst row of edge_index
    atomicAdd(&deg[d], 1.0f);
    atomicAdd(&asum[2 * d], eattr[2 * e]);
    atomicAdd(&asum[2 * d + 1], eattr[2 * e + 1]);
}

// Single-block prefix scan over per-dst counts (deg + 1 self-loop) -> row_ptr, cur
__global__ void scan_kernel(const float* __restrict__ deg, int* row_ptr, int* cur, int n) {
    __shared__ int sums[1024];
    __shared__ int offs[1025];
    int tid = threadIdx.x;
    int per = (n + 1023) / 1024;
    int s0 = tid * per;
    int s1 = s0 + per; if (s1 > n) s1 = n;
    int s = 0;
    for (int i = s0; i < s1; i++) s += (int)deg[i] + 1;
    sums[tid] = s;
    __syncthreads();
    if (tid == 0) {
        int run = 0;
        for (int i = 0; i < 1024; i++) { offs[i] = run; run += sums[i]; }
        offs[1024] = run;
    }
    __syncthreads();
    int run = offs[tid];
    for (int i = s0; i < s1; i++) {
        row_ptr[i] = run; cur[i] = run;
        run += (int)deg[i] + 1;
    }
    if (tid == 0) row_ptr[n] = offs[1024];
}

// Scatter edges (and self-loops with mean attr) into CSR-by-dst
__global__ void scatter_kernel(const int* __restrict__ ei, const float* __restrict__ eattr,
                               const float* __restrict__ deg, const float* __restrict__ asum,
                               int* cur, int* csr_src, float* csr_ea, int E, int n) {
    int i = blockIdx.x * blockDim.x + threadIdx.x;
    if (i >= E + n) return;
    if (i < E) {
        int d = ei[E + i];
        int pos = atomicAdd(&cur[d], 1);
        csr_src[pos] = ei[i];
        csr_ea[2 * pos] = eattr[2 * i];
        csr_ea[2 * pos + 1] = eattr[2 * i + 1];
    } else {
        int nd = i - E;
        float dv = fmaxf(deg[nd], 1.0f);
        int pos = atomicAdd(&cur[nd], 1);
        csr_src[pos] = nd;
        csr_ea[2 * pos] = asum[2 * nd] / dv;
        csr_ea[2 * pos + 1] = asum[2 * nd + 1] / dv;
    }
}

// ---------------------------------------------------------------------------
// Generic fp32 tiled GEMM: C[M,N] = A[M,K]@B[K,N] (+bias) (+exact GELU)
// 64x64 tile, 256 threads, 4x4 microtile. N,K multiples of 16/64 per our shapes.
// ---------------------------------------------------------------------------
template <int ACT>
__global__ __launch_bounds__(256) void gemm_f32(const float* __restrict__ A,
                                                const float* __restrict__ B,
                                                const float* __restrict__ bias,
                                                float* __restrict__ C,
                                                int M, int N, int K) {
    const int BM = 64, BN = 64, BK = 16;
    __shared__ float As[BK][BM + 1];
    __shared__ float Bs[BK][BN];
    int tid = threadIdx.x;
    int tx = tid & 15, ty = tid >> 4;
    int rowBase = blockIdx.y * BM;
    int colBase = blockIdx.x * BN;
    float acc[4][4] = {};
    for (int k0 = 0; k0 < K; k0 += BK) {
#pragma unroll
        for (int t = 0; t < 4; t++) {
            int idx = tid + t * 256;          // 0..1023
            int m = idx >> 4, k = idx & 15;   // A tile 64x16
            int row = rowBase + m;
            As[k][m] = (row < M) ? A[(size_t)row * K + k0 + k] : 0.0f;
        }
#pragma unroll
        for (int t = 0; t < 4; t++) {
            int idx = tid + t * 256;
            int k = idx >> 6, nn = idx & 63;  // B tile 16x64
            Bs[k][nn] = B[(size_t)(k0 + k) * N + colBase + nn];
        }
        __syncthreads();
#pragma unroll
        for (int k = 0; k < BK; k++) {
            float a[4], b[4];
#pragma unroll
            for (int i = 0; i < 4; i++) a[i] = As[k][ty * 4 + i];
#pragma unroll
            for (int j = 0; j < 4; j++) b[j] = Bs[k][tx * 4 + j];
#pragma unroll
            for (int i = 0; i < 4; i++)
#pragma unroll
                for (int j = 0; j < 4; j++) acc[i][j] += a[i] * b[j];
        }
        __syncthreads();
    }
#pragma unroll
    for (int i = 0; i < 4; i++) {
        int row = rowBase + ty * 4 + i;
        if (row >= M) continue;
#pragma unroll
        for (int j = 0; j < 4; j++) {
            int col = colBase + tx * 4 + j;
            float v = acc[i][j] + (bias ? bias[col] : 0.0f);
            if (ACT == 1) v = 0.5f * v * (1.0f + erff(v * 0.70710678118654752f));
            C[(size_t)row * N + col] = v;
        }
    }
}

// ---------------------------------------------------------------------------
// GATv2 attention + aggregation: one wave per dst node, online softmax.
// Each lane owns 8 channels of the 512 (head = lane/16).
// OUT may alias XR (each node's xr is read before its own write).
// ---------------------------------------------------------------------------
__global__ __launch_bounds__(256) void gat_edge_kernel(
    const float* __restrict__ XL, const float* XR,
    const int* __restrict__ row_ptr, const int* __restrict__ csr_src,
    const float* __restrict__ csr_ea,
    const float* __restrict__ We,    // [2,512]
    const float* __restrict__ attW,  // [512]
    const float* __restrict__ cbias, // [512] (concat) or [128]
    float* OUT, int n, int concat) {
    __shared__ float sWe0[HH], sWe1[HH], sAtt[HH], sCb[HH];
    int tid = threadIdx.x;
    for (int i = tid; i < HH; i += 256) {
        sWe0[i] = We[i];
        sWe1[i] = We[HH + i];
        sAtt[i] = attW[i];
    }
    int cbn = concat ? HH : HDIM;
    for (int i = tid; i < cbn; i += 256) sCb[i] = cbias[i];
    __syncthreads();

    int wave = tid >> 6, lane = tid & 63;
    int node = blockIdx.x * 4 + wave;
    if (node >= n) return;
    int c0 = lane * 8;

    float xr8[8], att8[8], w08[8], w18[8];
    {
        const float* xp = XR + (size_t)node * HH + c0;
        float4 a0 = *(const float4*)xp;
        float4 a1 = *(const float4*)(xp + 4);
        xr8[0]=a0.x; xr8[1]=a0.y; xr8[2]=a0.z; xr8[3]=a0.w;
        xr8[4]=a1.x; xr8[5]=a1.y; xr8[6]=a1.z; xr8[7]=a1.w;
#pragma unroll
        for (int k = 0; k < 8; k++) {
            att8[k] = sAtt[c0 + k];
            w08[k] = sWe0[c0 + k];
            w18[k] = sWe1[c0 + k];
        }
    }

    float acc[8] = {0,0,0,0,0,0,0,0};
    float m = -INFINITY, l = 0.0f;
    int beg = row_ptr[node], end = row_ptr[node + 1];
    for (int j = beg; j < end; j++) {
        int s = csr_src[j];
        float ea0 = csr_ea[2 * j];
        float ea1 = csr_ea[2 * j + 1];
        const float* xp = XL + (size_t)s * HH + c0;
        float4 a0 = *(const float4*)xp;
        float4 a1 = *(const float4*)(xp + 4);
        float xl8[8] = {a0.x, a0.y, a0.z, a0.w, a1.x, a1.y, a1.z, a1.w};
        float part = 0.0f;
#pragma unroll
        for (int k = 0; k < 8; k++) {
            float v = xl8[k] + xr8[k] + ea0 * w08[k] + ea1 * w18[k];
            v = (v > 0.0f) ? v : NEG_SLOPE * v;
            part += v * att8[k];
        }
        // reduce across the 16 lanes of this head
        part += __shfl_xor(part, 1);
        part += __shfl_xor(part, 2);
        part += __shfl_xor(part, 4);
        part += __shfl_xor(part, 8);
        float score = part;
        float mnew = fmaxf(m, score);
        float scale = expf(m - mnew);   // first iter: exp(-inf)=0
        float p = expf(score - mnew);
        l = l * scale + p;
#pragma unroll
        for (int k = 0; k < 8; k++) acc[k] = acc[k] * scale + p * xl8[k];
        m = mnew;
    }
    float inv = 1.0f / (l + 1e-16f);
    if (concat) {
        float o8[8];
#pragma unroll
        for (int k = 0; k < 8; k++) o8[k] = acc[k] * inv + sCb[c0 + k];
        float* op = OUT + (size_t)node * HH + c0;
        *(float4*)op = make_float4(o8[0], o8[1], o8[2], o8[3]);
        *(float4*)(op + 4) = make_float4(o8[4], o8[5], o8[6], o8[7]);
    } else {
        float o8[8];
#pragma unroll
        for (int k = 0; k < 8; k++) {
            float v = acc[k] * inv;
            v += __shfl_xor(v, 16);
            v += __shfl_xor(v, 32);
            o8[k] = v;
        }
        if (lane < 16) {
#pragma unroll
            for (int k = 0; k < 8; k++)
                OUT[(size_t)node * HDIM + c0 + k] = o8[k] * 0.25f + sCb[c0 + k];
        }
    }
}

// ---------------------------------------------------------------------------
// LayerNorm over last dim (128) of (X + R), one wave per row.
// OUT may alias X (each thread reads its own elems before writing them).
// ---------------------------------------------------------------------------
__global__ __launch_bounds__(256) void ln_res_kernel(const float* X, const float* R,
                                                     const float* __restrict__ g,
                                                     const float* __restrict__ b,
                                                     float* OUT, int n) {
    int wave = threadIdx.x >> 6, lane = threadIdx.x & 63;
    int row = blockIdx.x * 4 + wave;
    if (row >= n) return;
    int c = lane * 2;
    size_t base = (size_t)row * HDIM;
    float x0 = X[base + c] + R[base + c];
    float x1 = X[base + c + 1] + R[base + c + 1];
    float s = x0 + x1;
#pragma unroll
    for (int off = 1; off < 64; off <<= 1) s += __shfl_xor(s, off);
    float mu = s * (1.0f / HDIM);
    float d0 = x0 - mu, d1 = x1 - mu;
    float vs = d0 * d0 + d1 * d1;
#pragma unroll
    for (int off = 1; off < 64; off <<= 1) vs += __shfl_xor(vs, off);
    float invstd = rsqrtf(vs * (1.0f / HDIM) + 1e-5f);
    OUT[base + c] = d0 * invstd * g[c] + b[c];
    OUT[base + c + 1] = d1 * invstd * g[c + 1] + b[c + 1];
}

// ---------------------------------------------------------------------------
extern "C" void kernel_launch(void* const* d_in, const int* in_sizes, int n_in,
                              void* d_out, int out_size, void* d_ws, size_t ws_size,
                              hipStream_t stream) {
    const float* x        = (const float*)d_in[0];
    const int*   ei       = (const int*)d_in[1];
    const float* eattr    = (const float*)d_in[2];
    const float* emb_w    = (const float*)d_in[3];
    const float* emb_b    = (const float*)d_in[4];
    const float* lin_l    = (const float*)d_in[5];
    const float* lin_r    = (const float*)d_in[6];
    const float* lin_edge = (const float*)d_in[7];
    const float* attw     = (const float*)d_in[8];
    const float* cb01     = (const float*)d_in[9];
    const float* cb2      = (const float*)d_in[10];
    const float* proj_w   = (const float*)d_in[11];
    const float* proj_b   = (const float*)d_in[12];
    const float* n1g      = (const float*)d_in[13];
    const float* n1b      = (const float*)d_in[14];
    const float* n2g      = (const float*)d_in[15];
    const float* n2b      = (const float*)d_in[16];
    const float* fw1      = (const float*)d_in[17];
    const float* fb1      = (const float*)d_in[18];
    const float* fw2      = (const float*)d_in[19];
    const float* fb2      = (const float*)d_in[20];
    float* out = (float*)d_out;

    const int n = in_sizes[0] / IN_DIM;   // 20000
    const int E = in_sizes[2] / 2;        // 320000
    const int EP = E + n;

    // Workspace carve-up (256B-aligned chunks)
    size_t off = 0;
    auto alloc = [&](size_t bytes) {
        void* p = (char*)d_ws + off;
        off += (bytes + 255) & ~(size_t)255;
        return p;
    };
    float* deg     = (float*)alloc((size_t)n * 4);
    float* asum    = (float*)alloc((size_t)2 * n * 4);
    int*   row_ptr = (int*)alloc((size_t)(n + 1) * 4);
    int*   cur     = (int*)alloc((size_t)n * 4);
    int*   csr_src = (int*)alloc((size_t)EP * 4);
    float* csr_ea  = (float*)alloc((size_t)2 * EP * 4);
    float* H0      = (float*)alloc((size_t)n * HDIM * 4);
    float* H1      = (float*)alloc((size_t)n * HDIM * 4);
    float* MID     = (float*)alloc((size_t)n * FFH * 4);
    float* XL      = (float*)alloc((size_t)n * HH * 4);
    float* XR      = (float*)alloc((size_t)n * HH * 4);
    (void)ws_size;

    // ---- CSR build (per-call; ws is re-poisoned between launches) ----
    hipMemsetAsync(deg, 0, (size_t)n * 4, stream);
    hipMemsetAsync(asum, 0, (size_t)2 * n * 4, stream);
    deg_kernel<<<(E + 255) / 256, 256, 0, stream>>>(ei, eattr, deg, asum, E);
    scan_kernel<<<1, 1024, 0, stream>>>(deg, row_ptr, cur, n);
    scatter_kernel<<<(EP + 255) / 256, 256, 0, stream>>>(ei, eattr, deg, asum, cur,
                                                         csr_src, csr_ea, E, n);

    auto gemm = [&](const float* A, const float* B, const float* bias, float* C,
                    int M, int Nn, int K, int act) {
        dim3 grid(Nn / 64, (M + 63) / 64);
        if (act)
            gemm_f32<1><<<grid, 256, 0, stream>>>(A, B, bias, C, M, Nn, K);
        else
            gemm_f32<0><<<grid, 256, 0, stream>>>(A, B, bias, C, M, Nn, K);
    };

    // ---- Embedding: H0 = x @ emb_w + emb_b ----
    gemm(x, emb_w, emb_b, H0, n, HDIM, IN_DIM, 0);

    // ---- 3 GATv2 + FFN layers ----
    for (int i = 0; i < 3; i++) {
        int concat = (i < 2);
        gemm(H0, lin_l + (size_t)i * HDIM * HH, nullptr, XL, n, HH, HDIM, 0);
        gemm(H0, lin_r + (size_t)i * HDIM * HH, nullptr, XR, n, HH, HDIM, 0);
        float* gout = concat ? XR : H1;   // concat layers write over XR in place
        gat_edge_kernel<<<(n + 3) / 4, 256, 0, stream>>>(
            XL, XR, row_ptr, csr_src, csr_ea,
            lin_edge + (size_t)i * 2 * HH, attw + (size_t)i * HH,
            concat ? (cb01 + (size_t)i * HH) : cb2, gout, n, concat);
        if (concat)
            gemm(XR, proj_w + (size_t)i * HH * HDIM, proj_b + (size_t)i * HDIM,
                 H1, n, HDIM, HH, 0);
        ln_res_kernel<<<(n + 3) / 4, 256, 0, stream>>>(
            H1, H0, n1g + (size_t)i * HDIM, n1b + (size_t)i * HDIM, H1, n);
        gemm(H1, fw1 + (size_t)i * HDIM * FFH, fb1 + (size_t)i * FFH, MID, n, FFH, HDIM, 1);
        gemm(MID, fw2 + (size_t)i * FFH * HDIM, fb2 + (size_t)i * HDIM, H0, n, HDIM, FFH, 0);
        float* lnout = (i == 2) ? out : H0;
        ln_res_kernel<<<(n + 3) / 4, 256, 0, stream>>>(
            H0, H1, n2g + (size_t)i * HDIM, n2b + (size_t)i * HDIM, lnout, n);
    }
}

// Round 2
// 1112.651 us; speedup vs baseline: 1.1260x; 1.1260x over previous
//
#include <hip/hip_runtime.h>
#include <math.h>

// Problem constants
#define IN_DIM 16
#define HDIM   128
#define HEADS  4
#define HH     512   // HEADS*HDIM
#define FFH    256   // 2*HDIM
#define NEG_SLOPE 0.2f

typedef _Float16 half8 __attribute__((ext_vector_type(8)));
typedef float f32x4 __attribute__((ext_vector_type(4)));

// ---------------------------------------------------------------------------
// Preprocess: degree + edge_attr sums (for self-loop fill_value='mean')
// ---------------------------------------------------------------------------
__global__ void deg_kernel(const int* __restrict__ ei, const float* __restrict__ eattr,
                           float* deg, float* asum, int E) {
    int e = blockIdx.x * blockDim.x + threadIdx.x;
    if (e >= E) return;
    int d = ei[E + e];               // dst row of edge_index
    atomicAdd(&deg[d], 1.0f);
    atomicAdd(&asum[2 * d], eattr[2 * e]);
    atomicAdd(&asum[2 * d + 1], eattr[2 * e + 1]);
}

// Single-block prefix scan over per-dst counts (deg + 1 self-loop) -> row_ptr, cur
__global__ void scan_kernel(const float* __restrict__ deg, int* row_ptr, int* cur, int n) {
    __shared__ int sums[1024];
    __shared__ int offs[1025];
    int tid = threadIdx.x;
    int per = (n + 1023) / 1024;
    int s0 = tid * per;
    int s1 = s0 + per; if (s1 > n) s1 = n;
    int s = 0;
    for (int i = s0; i < s1; i++) s += (int)deg[i] + 1;
    sums[tid] = s;
    __syncthreads();
    if (tid == 0) {
        int run = 0;
        for (int i = 0; i < 1024; i++) { offs[i] = run; run += sums[i]; }
        offs[1024] = run;
    }
    __syncthreads();
    int run = offs[tid];
    for (int i = s0; i < s1; i++) {
        row_ptr[i] = run; cur[i] = run;
        run += (int)deg[i] + 1;
    }
    if (tid == 0) row_ptr[n] = offs[1024];
}

// Scatter edges (and self-loops with mean attr) into CSR-by-dst
__global__ void scatter_kernel(const int* __restrict__ ei, const float* __restrict__ eattr,
                               const float* __restrict__ deg, const float* __restrict__ asum,
                               int* cur, int* csr_src, float* csr_ea, int E, int n) {
    int i = blockIdx.x * blockDim.x + threadIdx.x;
    if (i >= E + n) return;
    if (i < E) {
        int d = ei[E + i];
        int pos = atomicAdd(&cur[d], 1);
        csr_src[pos] = ei[i];
        csr_ea[2 * pos] = eattr[2 * i];
        csr_ea[2 * pos + 1] = eattr[2 * i + 1];
    } else {
        int nd = i - E;
        float dv = fmaxf(deg[nd], 1.0f);
        int pos = atomicAdd(&cur[nd], 1);
        csr_src[pos] = nd;
        csr_ea[2 * pos] = asum[2 * nd] / dv;
        csr_ea[2 * pos + 1] = asum[2 * nd + 1] / dv;
    }
}

// ---------------------------------------------------------------------------
// MFMA f16 GEMM: C[M,N] = A[M,K]@B[K,N] (+bias) (+exact GELU)
// A,B fp32 in memory, converted to f16 during LDS staging; fp32 accumulate.
// Block tile 128x64, BK=32, 4 waves, each wave 32x64 via 2x4 mfma_16x16x32.
// N must be a multiple of 64; K a multiple of 16 (zero-padded to BK).
// ---------------------------------------------------------------------------
template <int ACT>
__global__ __launch_bounds__(256) void gemm_mfma(const float* __restrict__ A,
                                                 const float* __restrict__ B,
                                                 const float* __restrict__ bias,
                                                 float* __restrict__ C,
                                                 int M, int N, int K) {
    const int BM = 128, BN = 64, BK = 32, PAD = 8;
    __shared__ _Float16 As[BM][BK + PAD];   // row stride 80B (16B-aligned)
    __shared__ _Float16 Bs[BN][BK + PAD];   // transposed: [n][k]
    int tid = threadIdx.x;
    int wave = tid >> 6, lane = tid & 63;
    int quad = lane >> 4, l16 = lane & 15;
    int mBase = blockIdx.y * BM;
    int n0 = blockIdx.x * BN;

    f32x4 acc[2][4] = {};

    for (int k0 = 0; k0 < K; k0 += BK) {
        // ---- Stage A: 128x32 fp32 -> f16 (4 float4 per thread) ----
#pragma unroll
        for (int t = 0; t < 4; t++) {
            int idx = tid + t * 256;          // 0..1023
            int r = idx >> 3;                 // 0..127
            int c4 = (idx & 7) * 4;           // 0..28
            int grow = mBase + r;
            float4 v = make_float4(0.f, 0.f, 0.f, 0.f);
            if (grow < M && (k0 + c4) < K)
                v = *(const float4*)(A + (size_t)grow * K + k0 + c4);
            As[r][c4 + 0] = (_Float16)v.x;
            As[r][c4 + 1] = (_Float16)v.y;
            As[r][c4 + 2] = (_Float16)v.z;
            As[r][c4 + 3] = (_Float16)v.w;
        }
        // ---- Stage B transposed: thread owns (n, kgroup of 8) ----
        {
            int nn = tid & 63;
            int kb = (tid >> 6) * 8;          // 0,8,16,24
            half8 bv;
#pragma unroll
            for (int kk = 0; kk < 8; kk++) {
                int k = kb + kk;
                float v = (k0 + k < K) ? B[(size_t)(k0 + k) * N + n0 + nn] : 0.0f;
                bv[kk] = (_Float16)v;
            }
            *(half8*)&Bs[nn][kb] = bv;
        }
        __syncthreads();

        // ---- Compute: wave's 32x64 region, one mfma per 16x16 tile ----
        half8 a[2], b[4];
#pragma unroll
        for (int i = 0; i < 2; i++)
            a[i] = *(const half8*)&As[wave * 32 + i * 16 + l16][quad * 8];
#pragma unroll
        for (int j = 0; j < 4; j++)
            b[j] = *(const half8*)&Bs[j * 16 + l16][quad * 8];
#pragma unroll
        for (int i = 0; i < 2; i++)
#pragma unroll
            for (int j = 0; j < 4; j++)
                acc[i][j] = __builtin_amdgcn_mfma_f32_16x16x32_f16(a[i], b[j], acc[i][j], 0, 0, 0);
        __syncthreads();
    }

    // ---- Epilogue: C/D layout col=lane&15, row=quad*4+reg ----
#pragma unroll
    for (int i = 0; i < 2; i++) {
#pragma unroll
        for (int r = 0; r < 4; r++) {
            int row = mBase + wave * 32 + i * 16 + quad * 4 + r;
            if (row >= M) continue;
#pragma unroll
            for (int j = 0; j < 4; j++) {
                int col = n0 + j * 16 + l16;
                float v = acc[i][j][r] + (bias ? bias[col] : 0.0f);
                if (ACT == 1) v = 0.5f * v * (1.0f + erff(v * 0.70710678118654752f));
                C[(size_t)row * N + col] = v;
            }
        }
    }
}

// ---------------------------------------------------------------------------
// GATv2 attention + aggregation: one wave per dst node, online softmax.
// Each lane owns 8 channels of the 512 (head = lane/16).
// OUT may alias XR (each node's xr is read before its own write).
// ---------------------------------------------------------------------------
__global__ __launch_bounds__(256) void gat_edge_kernel(
    const float* __restrict__ XL, const float* XR,
    const int* __restrict__ row_ptr, const int* __restrict__ csr_src,
    const float* __restrict__ csr_ea,
    const float* __restrict__ We,    // [2,512]
    const float* __restrict__ attW,  // [512]
    const float* __restrict__ cbias, // [512] (concat) or [128]
    float* OUT, int n, int concat) {
    __shared__ float sWe0[HH], sWe1[HH], sAtt[HH], sCb[HH];
    int tid = threadIdx.x;
    for (int i = tid; i < HH; i += 256) {
        sWe0[i] = We[i];
        sWe1[i] = We[HH + i];
        sAtt[i] = attW[i];
    }
    int cbn = concat ? HH : HDIM;
    for (int i = tid; i < cbn; i += 256) sCb[i] = cbias[i];
    __syncthreads();

    int wave = tid >> 6, lane = tid & 63;
    int node = blockIdx.x * 4 + wave;
    if (node >= n) return;
    int c0 = lane * 8;

    float xr8[8], att8[8], w08[8], w18[8];
    {
        const float* xp = XR + (size_t)node * HH + c0;
        float4 a0 = *(const float4*)xp;
        float4 a1 = *(const float4*)(xp + 4);
        xr8[0]=a0.x; xr8[1]=a0.y; xr8[2]=a0.z; xr8[3]=a0.w;
        xr8[4]=a1.x; xr8[5]=a1.y; xr8[6]=a1.z; xr8[7]=a1.w;
#pragma unroll
        for (int k = 0; k < 8; k++) {
            att8[k] = sAtt[c0 + k];
            w08[k] = sWe0[c0 + k];
            w18[k] = sWe1[c0 + k];
        }
    }

    float acc[8] = {0,0,0,0,0,0,0,0};
    float m = -INFINITY, l = 0.0f;
    int beg = row_ptr[node], end = row_ptr[node + 1];
    for (int j = beg; j < end; j++) {
        int s = csr_src[j];
        float ea0 = csr_ea[2 * j];
        float ea1 = csr_ea[2 * j + 1];
        const float* xp = XL + (size_t)s * HH + c0;
        float4 a0 = *(const float4*)xp;
        float4 a1 = *(const float4*)(xp + 4);
        float xl8[8] = {a0.x, a0.y, a0.z, a0.w, a1.x, a1.y, a1.z, a1.w};
        float part = 0.0f;
#pragma unroll
        for (int k = 0; k < 8; k++) {
            float v = xl8[k] + xr8[k] + ea0 * w08[k] + ea1 * w18[k];
            v = (v > 0.0f) ? v : NEG_SLOPE * v;
            part += v * att8[k];
        }
        // reduce across the 16 lanes of this head
        part += __shfl_xor(part, 1);
        part += __shfl_xor(part, 2);
        part += __shfl_xor(part, 4);
        part += __shfl_xor(part, 8);
        float score = part;
        float mnew = fmaxf(m, score);
        float scale = expf(m - mnew);   // first iter: exp(-inf)=0
        float p = expf(score - mnew);
        l = l * scale + p;
#pragma unroll
        for (int k = 0; k < 8; k++) acc[k] = acc[k] * scale + p * xl8[k];
        m = mnew;
    }
    float inv = 1.0f / (l + 1e-16f);
    if (concat) {
        float o8[8];
#pragma unroll
        for (int k = 0; k < 8; k++) o8[k] = acc[k] * inv + sCb[c0 + k];
        float* op = OUT + (size_t)node * HH + c0;
        *(float4*)op = make_float4(o8[0], o8[1], o8[2], o8[3]);
        *(float4*)(op + 4) = make_float4(o8[4], o8[5], o8[6], o8[7]);
    } else {
        float o8[8];
#pragma unroll
        for (int k = 0; k < 8; k++) {
            float v = acc[k] * inv;
            v += __shfl_xor(v, 16);
            v += __shfl_xor(v, 32);
            o8[k] = v;
        }
        if (lane < 16) {
#pragma unroll
            for (int k = 0; k < 8; k++)
                OUT[(size_t)node * HDIM + c0 + k] = o8[k] * 0.25f + sCb[c0 + k];
        }
    }
}

// ---------------------------------------------------------------------------
// LayerNorm over last dim (128) of (X + R), one wave per row.
// OUT may alias X (each thread reads its own elems before writing them).
// ---------------------------------------------------------------------------
__global__ __launch_bounds__(256) void ln_res_kernel(const float* X, const float* R,
                                                     const float* __restrict__ g,
                                                     const float* __restrict__ b,
                                                     float* OUT, int n) {
    int wave = threadIdx.x >> 6, lane = threadIdx.x & 63;
    int row = blockIdx.x * 4 + wave;
    if (row >= n) return;
    int c = lane * 2;
    size_t base = (size_t)row * HDIM;
    float x0 = X[base + c] + R[base + c];
    float x1 = X[base + c + 1] + R[base + c + 1];
    float s = x0 + x1;
#pragma unroll
    for (int off = 1; off < 64; off <<= 1) s += __shfl_xor(s, off);
    float mu = s * (1.0f / HDIM);
    float d0 = x0 - mu, d1 = x1 - mu;
    float vs = d0 * d0 + d1 * d1;
#pragma unroll
    for (int off = 1; off < 64; off <<= 1) vs += __shfl_xor(vs, off);
    float invstd = rsqrtf(vs * (1.0f / HDIM) + 1e-5f);
    OUT[base + c] = d0 * invstd * g[c] + b[c];
    OUT[base + c + 1] = d1 * invstd * g[c + 1] + b[c + 1];
}

// ---------------------------------------------------------------------------
extern "C" void kernel_launch(void* const* d_in, const int* in_sizes, int n_in,
                              void* d_out, int out_size, void* d_ws, size_t ws_size,
                              hipStream_t stream) {
    const float* x        = (const float*)d_in[0];
    const int*   ei       = (const int*)d_in[1];
    const float* eattr    = (const float*)d_in[2];
    const float* emb_w    = (const float*)d_in[3];
    const float* emb_b    = (const float*)d_in[4];
    const float* lin_l    = (const float*)d_in[5];
    const float* lin_r    = (const float*)d_in[6];
    const float* lin_edge = (const float*)d_in[7];
    const float* attw     = (const float*)d_in[8];
    const float* cb01     = (const float*)d_in[9];
    const float* cb2      = (const float*)d_in[10];
    const float* proj_w   = (const float*)d_in[11];
    const float* proj_b   = (const float*)d_in[12];
    const float* n1g      = (const float*)d_in[13];
    const float* n1b      = (const float*)d_in[14];
    const float* n2g      = (const float*)d_in[15];
    const float* n2b      = (const float*)d_in[16];
    const float* fw1      = (const float*)d_in[17];
    const float* fb1      = (const float*)d_in[18];
    const float* fw2      = (const float*)d_in[19];
    const float* fb2      = (const float*)d_in[20];
    float* out = (float*)d_out;

    const int n = in_sizes[0] / IN_DIM;   // 20000
    const int E = in_sizes[2] / 2;        // 320000
    const int EP = E + n;

    // Workspace carve-up (256B-aligned chunks)
    size_t off = 0;
    auto alloc = [&](size_t bytes) {
        void* p = (char*)d_ws + off;
        off += (bytes + 255) & ~(size_t)255;
        return p;
    };
    float* deg     = (float*)alloc((size_t)n * 4);
    float* asum    = (float*)alloc((size_t)2 * n * 4);
    int*   row_ptr = (int*)alloc((size_t)(n + 1) * 4);
    int*   cur     = (int*)alloc((size_t)n * 4);
    int*   csr_src = (int*)alloc((size_t)EP * 4);
    float* csr_ea  = (float*)alloc((size_t)2 * EP * 4);
    float* H0      = (float*)alloc((size_t)n * HDIM * 4);
    float* H1      = (float*)alloc((size_t)n * HDIM * 4);
    float* MID     = (float*)alloc((size_t)n * FFH * 4);
    float* XL      = (float*)alloc((size_t)n * HH * 4);
    float* XR      = (float*)alloc((size_t)n * HH * 4);
    (void)ws_size;

    // ---- CSR build (per-call; ws is re-poisoned between launches) ----
    hipMemsetAsync(deg, 0, (size_t)n * 4, stream);
    hipMemsetAsync(asum, 0, (size_t)2 * n * 4, stream);
    deg_kernel<<<(E + 255) / 256, 256, 0, stream>>>(ei, eattr, deg, asum, E);
    scan_kernel<<<1, 1024, 0, stream>>>(deg, row_ptr, cur, n);
    scatter_kernel<<<(EP + 255) / 256, 256, 0, stream>>>(ei, eattr, deg, asum, cur,
                                                         csr_src, csr_ea, E, n);

    auto gemm = [&](const float* A, const float* B, const float* bias, float* C,
                    int M, int Nn, int K, int act) {
        dim3 grid(Nn / 64, (M + 127) / 128);
        if (act)
            gemm_mfma<1><<<grid, 256, 0, stream>>>(A, B, bias, C, M, Nn, K);
        else
            gemm_mfma<0><<<grid, 256, 0, stream>>>(A, B, bias, C, M, Nn, K);
    };

    // ---- Embedding: H0 = x @ emb_w + emb_b ----
    gemm(x, emb_w, emb_b, H0, n, HDIM, IN_DIM, 0);

    // ---- 3 GATv2 + FFN layers ----
    for (int i = 0; i < 3; i++) {
        int concat = (i < 2);
        gemm(H0, lin_l + (size_t)i * HDIM * HH, nullptr, XL, n, HH, HDIM, 0);
        gemm(H0, lin_r + (size_t)i * HDIM * HH, nullptr, XR, n, HH, HDIM, 0);
        float* gout = concat ? XR : H1;   // concat layers write over XR in place
        gat_edge_kernel<<<(n + 3) / 4, 256, 0, stream>>>(
            XL, XR, row_ptr, csr_src, csr_ea,
            lin_edge + (size_t)i * 2 * HH, attw + (size_t)i * HH,
            concat ? (cb01 + (size_t)i * HH) : cb2, gout, n, concat);
        if (concat)
            gemm(XR, proj_w + (size_t)i * HH * HDIM, proj_b + (size_t)i * HDIM,
                 H1, n, HDIM, HH, 0);
        ln_res_kernel<<<(n + 3) / 4, 256, 0, stream>>>(
            H1, H0, n1g + (size_t)i * HDIM, n1b + (size_t)i * HDIM, H1, n);
        gemm(H1, fw1 + (size_t)i * HDIM * FFH, fb1 + (size_t)i * FFH, MID, n, FFH, HDIM, 1);
        gemm(MID, fw2 + (size_t)i * FFH * HDIM, fb2 + (size_t)i * HDIM, H0, n, HDIM, FFH, 0);
        float* lnout = (i == 2) ? out : H0;
        ln_res_kernel<<<(n + 3) / 4, 256, 0, stream>>>(
            H0, H1, n2g + (size_t)i * HDIM, n2b + (size_t)i * HDIM, lnout, n);
    }
}

// Round 3
// 787.585 us; speedup vs baseline: 1.5908x; 1.4127x over previous
//
#include <hip/hip_runtime.h>
#include <math.h>

#define IN_DIM 16
#define HDIM   128
#define HEADS  4
#define HH     512   // HEADS*HDIM
#define FFH    256   // 2*HDIM
#define NEG_SLOPE 0.2f

typedef _Float16 half8 __attribute__((ext_vector_type(8)));
typedef float f32x4 __attribute__((ext_vector_type(4)));

// ---------------------------------------------------------------------------
// Weight convert+transpose: W[K][N] fp32 -> WT[N][K] f16.  N is a power of 2.
// ---------------------------------------------------------------------------
struct WDesc { const float* src; _Float16* dst; int K; int lgN; };
struct WDescs { WDesc d[15]; };
__global__ void wconv_kernel(WDescs ds) {
    WDesc w = ds.d[blockIdx.y];
    int N = 1 << w.lgN;
    int total = w.K << w.lgN;
    for (int idx = blockIdx.x * 256 + threadIdx.x; idx < total; idx += gridDim.x * 256) {
        int k = idx >> w.lgN, n2 = idx & (N - 1);
        w.dst[(size_t)n2 * w.K + k] = (_Float16)w.src[idx];
    }
}

// ---------------------------------------------------------------------------
// Preprocess: degree + edge_attr sums (self-loop fill_value='mean')
// ---------------------------------------------------------------------------
__global__ void deg_kernel(const int* __restrict__ ei, const float* __restrict__ eattr,
                           float* deg, float* asum, int E) {
    int e = blockIdx.x * blockDim.x + threadIdx.x;
    if (e >= E) return;
    int d = ei[E + e];
    atomicAdd(&deg[d], 1.0f);
    atomicAdd(&asum[2 * d], eattr[2 * e]);
    atomicAdd(&asum[2 * d + 1], eattr[2 * e + 1]);
}

__global__ void scan_kernel(const float* __restrict__ deg, int* row_ptr, int* cur, int n) {
    __shared__ int sums[1024];
    __shared__ int offs[1025];
    int tid = threadIdx.x;
    int per = (n + 1023) / 1024;
    int s0 = tid * per;
    int s1 = s0 + per; if (s1 > n) s1 = n;
    int s = 0;
    for (int i = s0; i < s1; i++) s += (int)deg[i] + 1;
    sums[tid] = s;
    __syncthreads();
    if (tid == 0) {
        int run = 0;
        for (int i = 0; i < 1024; i++) { offs[i] = run; run += sums[i]; }
        offs[1024] = run;
    }
    __syncthreads();
    int run = offs[tid];
    for (int i = s0; i < s1; i++) {
        row_ptr[i] = run; cur[i] = run;
        run += (int)deg[i] + 1;
    }
    if (tid == 0) row_ptr[n] = offs[1024];
}

__global__ void scatter_kernel(const int* __restrict__ ei, const float* __restrict__ eattr,
                               const float* __restrict__ deg, const float* __restrict__ asum,
                               int* cur, int* csr_src, float* csr_ea, int E, int n) {
    int i = blockIdx.x * blockDim.x + threadIdx.x;
    if (i >= E + n) return;
    if (i < E) {
        int d = ei[E + i];
        int pos = atomicAdd(&cur[d], 1);
        csr_src[pos] = ei[i];
        csr_ea[2 * pos] = eattr[2 * i];
        csr_ea[2 * pos + 1] = eattr[2 * i + 1];
    } else {
        int nd = i - E;
        float dv = fmaxf(deg[nd], 1.0f);
        int pos = atomicAdd(&cur[nd], 1);
        csr_src[pos] = nd;
        csr_ea[2 * pos] = asum[2 * nd] / dv;
        csr_ea[2 * pos + 1] = asum[2 * nd + 1] / dv;
    }
}

// ---------------------------------------------------------------------------
// MFMA f16 GEMM: C[M,N] = A[M,K] @ B[K,N] (+bias)(+GELU)
// B passed pre-converted/transposed f16 BT[N][K]. A fp32 or f16 (A16).
// Block tile 128x128, BK=32, 4 waves in 2x2, each wave 64x64 (16 mfma/k-step).
// N multiple of 128; K multiple of 8 (zero-padded to BK granularity of 8).
// ---------------------------------------------------------------------------
template <int ACT, int A16, int OUT16>
__global__ __launch_bounds__(256) void gemm_mfma(const void* __restrict__ Av,
                                                 const _Float16* __restrict__ BT,
                                                 const float* __restrict__ bias,
                                                 void* __restrict__ Cv,
                                                 int M, int N, int K) {
    const int BK = 32, PAD = 8;
    __shared__ _Float16 As[128][BK + PAD];
    __shared__ _Float16 Bs[128][BK + PAD];
    int tid = threadIdx.x;
    int wave = tid >> 6, lane = tid & 63;
    int quad = lane >> 4, l16 = lane & 15;
    int wrow = (wave >> 1) * 64, wcol = (wave & 1) * 64;
    int mBase = blockIdx.y * 128;
    int n0 = blockIdx.x * 128;

    f32x4 acc[4][4] = {};

    for (int k0 = 0; k0 < K; k0 += BK) {
        // ---- Stage A: 128 rows x 32 halfs ----
#pragma unroll
        for (int t = 0; t < 2; t++) {
            int idx = tid + t * 256;          // 0..511
            int r = idx >> 2;                 // 0..127
            int kb = (idx & 3) * 8;           // 0,8,16,24
            int grow = mBase + r;
            half8 hv = {};
            if (grow < M && (k0 + kb) < K) {
                if (A16) {
                    hv = *(const half8*)((const _Float16*)Av + (size_t)grow * K + k0 + kb);
                } else {
                    const float* ap = (const float*)Av + (size_t)grow * K + k0 + kb;
                    float4 v0 = *(const float4*)ap;
                    float4 v1 = *(const float4*)(ap + 4);
                    hv[0] = (_Float16)v0.x; hv[1] = (_Float16)v0.y;
                    hv[2] = (_Float16)v0.z; hv[3] = (_Float16)v0.w;
                    hv[4] = (_Float16)v1.x; hv[5] = (_Float16)v1.y;
                    hv[6] = (_Float16)v1.z; hv[7] = (_Float16)v1.w;
                }
            }
            *(half8*)&As[r][kb] = hv;
        }
        // ---- Stage B: 128 n-rows x 32 halfs from BT[N][K] ----
#pragma unroll
        for (int t = 0; t < 2; t++) {
            int idx = tid + t * 256;
            int r = idx >> 2;
            int kb = (idx & 3) * 8;
            half8 hv = {};
            if ((k0 + kb) < K)
                hv = *(const half8*)(BT + (size_t)(n0 + r) * K + k0 + kb);
            *(half8*)&Bs[r][kb] = hv;
        }
        __syncthreads();

        half8 a[4], b[4];
#pragma unroll
        for (int i = 0; i < 4; i++)
            a[i] = *(const half8*)&As[wrow + i * 16 + l16][quad * 8];
#pragma unroll
        for (int j = 0; j < 4; j++)
            b[j] = *(const half8*)&Bs[wcol + j * 16 + l16][quad * 8];
#pragma unroll
        for (int i = 0; i < 4; i++)
#pragma unroll
            for (int j = 0; j < 4; j++)
                acc[i][j] = __builtin_amdgcn_mfma_f32_16x16x32_f16(a[i], b[j], acc[i][j], 0, 0, 0);
        __syncthreads();
    }

    // ---- Epilogue: 16x16 C layout col=l16, row=quad*4+reg ----
#pragma unroll
    for (int i = 0; i < 4; i++) {
#pragma unroll
        for (int r = 0; r < 4; r++) {
            int row = mBase + wrow + i * 16 + quad * 4 + r;
            if (row >= M) continue;
#pragma unroll
            for (int j = 0; j < 4; j++) {
                int col = n0 + wcol + j * 16 + l16;
                float v = acc[i][j][r] + (bias ? bias[col] : 0.0f);
                if (ACT == 1) v = 0.5f * v * (1.0f + erff(v * 0.70710678118654752f));
                if (OUT16)
                    ((_Float16*)Cv)[(size_t)row * N + col] = (_Float16)v;
                else
                    ((float*)Cv)[(size_t)row * N + col] = v;
            }
        }
    }
}

// ---------------------------------------------------------------------------
// GATv2 attention + aggregation: one wave per dst node, online softmax,
// 2-edge unroll. XL/XR f16. Concat: writes f16 (may alias XR). Non-concat:
// head-mean written fp32 to OUT32.
// ---------------------------------------------------------------------------
__global__ __launch_bounds__(256) void gat_edge_kernel(
    const _Float16* __restrict__ XL, const _Float16* XR,
    const int* __restrict__ row_ptr, const int* __restrict__ csr_src,
    const float* __restrict__ csr_ea,
    const float* __restrict__ We,    // [2,512]
    const float* __restrict__ attW,  // [512]
    const float* __restrict__ cbias, // [512] or [128]
    _Float16* OUT16, float* OUT32, int n, int concat) {
    __shared__ float sWe0[HH], sWe1[HH], sAtt[HH], sCb[HH];
    int tid = threadIdx.x;
    for (int i = tid; i < HH; i += 256) {
        sWe0[i] = We[i];
        sWe1[i] = We[HH + i];
        sAtt[i] = attW[i];
    }
    int cbn = concat ? HH : HDIM;
    for (int i = tid; i < cbn; i += 256) sCb[i] = cbias[i];
    __syncthreads();

    int wave = tid >> 6, lane = tid & 63;
    int node = blockIdx.x * 4 + wave;
    if (node >= n) return;
    int c0 = lane * 8;

    float xr8[8], att8[8], w08[8], w18[8];
    {
        half8 h = *(const half8*)(XR + (size_t)node * HH + c0);
#pragma unroll
        for (int k = 0; k < 8; k++) {
            xr8[k] = (float)h[k];
            att8[k] = sAtt[c0 + k];
            w08[k] = sWe0[c0 + k];
            w18[k] = sWe1[c0 + k];
        }
    }

    float acc[8] = {0,0,0,0,0,0,0,0};
    float m = -INFINITY, l = 0.0f;
    int beg = row_ptr[node], end = row_ptr[node + 1];
    int j = beg;
    for (; j + 1 < end; j += 2) {
        int s0 = csr_src[j], s1 = csr_src[j + 1];
        float ea00 = csr_ea[2 * j],     ea01 = csr_ea[2 * j + 1];
        float ea10 = csr_ea[2 * j + 2], ea11 = csr_ea[2 * j + 3];
        half8 h0 = *(const half8*)(XL + (size_t)s0 * HH + c0);
        half8 h1 = *(const half8*)(XL + (size_t)s1 * HH + c0);
        float xl0[8], xl1[8];
        float p0 = 0.0f, p1 = 0.0f;
#pragma unroll
        for (int k = 0; k < 8; k++) {
            xl0[k] = (float)h0[k];
            xl1[k] = (float)h1[k];
            float v0 = xl0[k] + fmaf(ea00, w08[k], fmaf(ea01, w18[k], xr8[k]));
            float v1 = xl1[k] + fmaf(ea10, w08[k], fmaf(ea11, w18[k], xr8[k]));
            v0 = fmaxf(v0, NEG_SLOPE * v0);
            v1 = fmaxf(v1, NEG_SLOPE * v1);
            p0 = fmaf(v0, att8[k], p0);
            p1 = fmaf(v1, att8[k], p1);
        }
        p0 += __shfl_xor(p0, 1); p1 += __shfl_xor(p1, 1);
        p0 += __shfl_xor(p0, 2); p1 += __shfl_xor(p1, 2);
        p0 += __shfl_xor(p0, 4); p1 += __shfl_xor(p1, 4);
        p0 += __shfl_xor(p0, 8); p1 += __shfl_xor(p1, 8);
        float mnew = fmaxf(m, fmaxf(p0, p1));
        float scale = expf(m - mnew);
        float e0 = expf(p0 - mnew);
        float e1 = expf(p1 - mnew);
        l = l * scale + e0 + e1;
#pragma unroll
        for (int k = 0; k < 8; k++)
            acc[k] = fmaf(acc[k], scale, fmaf(e0, xl0[k], e1 * xl1[k]));
        m = mnew;
    }
    if (j < end) {
        int s0 = csr_src[j];
        float ea00 = csr_ea[2 * j], ea01 = csr_ea[2 * j + 1];
        half8 h0 = *(const half8*)(XL + (size_t)s0 * HH + c0);
        float xl0[8];
        float p0 = 0.0f;
#pragma unroll
        for (int k = 0; k < 8; k++) {
            xl0[k] = (float)h0[k];
            float v0 = xl0[k] + fmaf(ea00, w08[k], fmaf(ea01, w18[k], xr8[k]));
            v0 = fmaxf(v0, NEG_SLOPE * v0);
            p0 = fmaf(v0, att8[k], p0);
        }
        p0 += __shfl_xor(p0, 1);
        p0 += __shfl_xor(p0, 2);
        p0 += __shfl_xor(p0, 4);
        p0 += __shfl_xor(p0, 8);
        float mnew = fmaxf(m, p0);
        float scale = expf(m - mnew);
        float e0 = expf(p0 - mnew);
        l = l * scale + e0;
#pragma unroll
        for (int k = 0; k < 8; k++)
            acc[k] = fmaf(acc[k], scale, e0 * xl0[k]);
        m = mnew;
    }
    float inv = 1.0f / (l + 1e-16f);
    if (concat) {
        half8 o;
#pragma unroll
        for (int k = 0; k < 8; k++) o[k] = (_Float16)(acc[k] * inv + sCb[c0 + k]);
        *(half8*)(OUT16 + (size_t)node * HH + c0) = o;
    } else {
        float o8[8];
#pragma unroll
        for (int k = 0; k < 8; k++) {
            float v = acc[k] * inv;
            v += __shfl_xor(v, 16);
            v += __shfl_xor(v, 32);
            o8[k] = v;
        }
        if (lane < 16) {
#pragma unroll
            for (int k = 0; k < 8; k++)
                OUT32[(size_t)node * HDIM + c0 + k] = o8[k] * 0.25f + sCb[c0 + k];
        }
    }
}

// ---------------------------------------------------------------------------
// LayerNorm over last dim (128) of (X + R), one wave per row. fp32.
// ---------------------------------------------------------------------------
__global__ __launch_bounds__(256) void ln_res_kernel(const float* X, const float* R,
                                                     const float* __restrict__ g,
                                                     const float* __restrict__ b,
                                                     float* OUT, int n) {
    int wave = threadIdx.x >> 6, lane = threadIdx.x & 63;
    int row = blockIdx.x * 4 + wave;
    if (row >= n) return;
    int c = lane * 2;
    size_t base = (size_t)row * HDIM;
    float x0 = X[base + c] + R[base + c];
    float x1 = X[base + c + 1] + R[base + c + 1];
    float s = x0 + x1;
#pragma unroll
    for (int off = 1; off < 64; off <<= 1) s += __shfl_xor(s, off);
    float mu = s * (1.0f / HDIM);
    float d0 = x0 - mu, d1 = x1 - mu;
    float vs = d0 * d0 + d1 * d1;
#pragma unroll
    for (int off = 1; off < 64; off <<= 1) vs += __shfl_xor(vs, off);
    float invstd = rsqrtf(vs * (1.0f / HDIM) + 1e-5f);
    OUT[base + c] = d0 * invstd * g[c] + b[c];
    OUT[base + c + 1] = d1 * invstd * g[c + 1] + b[c + 1];
}

// ---------------------------------------------------------------------------
extern "C" void kernel_launch(void* const* d_in, const int* in_sizes, int n_in,
                              void* d_out, int out_size, void* d_ws, size_t ws_size,
                              hipStream_t stream) {
    const float* x        = (const float*)d_in[0];
    const int*   ei       = (const int*)d_in[1];
    const float* eattr    = (const float*)d_in[2];
    const float* emb_w    = (const float*)d_in[3];
    const float* emb_b    = (const float*)d_in[4];
    const float* lin_l    = (const float*)d_in[5];
    const float* lin_r    = (const float*)d_in[6];
    const float* lin_edge = (const float*)d_in[7];
    const float* attw     = (const float*)d_in[8];
    const float* cb01     = (const float*)d_in[9];
    const float* cb2      = (const float*)d_in[10];
    const float* proj_w   = (const float*)d_in[11];
    const float* proj_b   = (const float*)d_in[12];
    const float* n1g      = (const float*)d_in[13];
    const float* n1b      = (const float*)d_in[14];
    const float* n2g      = (const float*)d_in[15];
    const float* n2b      = (const float*)d_in[16];
    const float* fw1      = (const float*)d_in[17];
    const float* fb1      = (const float*)d_in[18];
    const float* fw2      = (const float*)d_in[19];
    const float* fb2      = (const float*)d_in[20];
    float* out = (float*)d_out;

    const int n = in_sizes[0] / IN_DIM;   // 20000
    const int E = in_sizes[2] / 2;        // 320000
    const int EP = E + n;

    size_t off = 0;
    auto alloc = [&](size_t bytes) {
        void* p = (char*)d_ws + off;
        off += (bytes + 255) & ~(size_t)255;
        return p;
    };
    float* deg     = (float*)alloc((size_t)n * 4);
    float* asum    = (float*)alloc((size_t)2 * n * 4);
    int*   row_ptr = (int*)alloc((size_t)(n + 1) * 4);
    int*   cur     = (int*)alloc((size_t)n * 4);
    int*   csr_src = (int*)alloc((size_t)EP * 4);
    float* csr_ea  = (float*)alloc((size_t)2 * EP * 4);
    float* H0      = (float*)alloc((size_t)n * HDIM * 4);
    float* H1      = (float*)alloc((size_t)n * HDIM * 4);
    _Float16* MID  = (_Float16*)alloc((size_t)n * FFH * 2);
    _Float16* XL   = (_Float16*)alloc((size_t)n * HH * 2);
    _Float16* XR   = (_Float16*)alloc((size_t)n * HH * 2);
    // transposed f16 weights
    _Float16* wt_emb  = (_Float16*)alloc((size_t)IN_DIM * HDIM * 2);
    _Float16* wt_ll   = (_Float16*)alloc((size_t)3 * HDIM * HH * 2);
    _Float16* wt_lr   = (_Float16*)alloc((size_t)3 * HDIM * HH * 2);
    _Float16* wt_proj = (_Float16*)alloc((size_t)2 * HH * HDIM * 2);
    _Float16* wt_f1   = (_Float16*)alloc((size_t)3 * HDIM * FFH * 2);
    _Float16* wt_f2   = (_Float16*)alloc((size_t)3 * FFH * HDIM * 2);
    (void)ws_size;

    // ---- Weight convert/transpose (15 matrices, one kernel) ----
    WDescs ds;
    int di = 0;
    ds.d[di++] = {emb_w, wt_emb, IN_DIM, 7};
    for (int i = 0; i < 3; i++) ds.d[di++] = {lin_l + (size_t)i * HDIM * HH, wt_ll + (size_t)i * HDIM * HH, HDIM, 9};
    for (int i = 0; i < 3; i++) ds.d[di++] = {lin_r + (size_t)i * HDIM * HH, wt_lr + (size_t)i * HDIM * HH, HDIM, 9};
    for (int i = 0; i < 2; i++) ds.d[di++] = {proj_w + (size_t)i * HH * HDIM, wt_proj + (size_t)i * HH * HDIM, HH, 7};
    for (int i = 0; i < 3; i++) ds.d[di++] = {fw1 + (size_t)i * HDIM * FFH, wt_f1 + (size_t)i * HDIM * FFH, HDIM, 8};
    for (int i = 0; i < 3; i++) ds.d[di++] = {fw2 + (size_t)i * FFH * HDIM, wt_f2 + (size_t)i * FFH * HDIM, FFH, 7};
    wconv_kernel<<<dim3(32, 15), 256, 0, stream>>>(ds);

    // ---- CSR build ----
    hipMemsetAsync(deg, 0, (size_t)n * 4, stream);
    hipMemsetAsync(asum, 0, (size_t)2 * n * 4, stream);
    deg_kernel<<<(E + 255) / 256, 256, 0, stream>>>(ei, eattr, deg, asum, E);
    scan_kernel<<<1, 1024, 0, stream>>>(deg, row_ptr, cur, n);
    scatter_kernel<<<(EP + 255) / 256, 256, 0, stream>>>(ei, eattr, deg, asum, cur,
                                                         csr_src, csr_ea, E, n);

    auto gemm = [&](const void* A, const _Float16* BT, const float* bias, void* C,
                    int M, int Nn, int K, int act, int a16, int o16) {
        dim3 grid(Nn / 128, (M + 127) / 128);
        if (a16) {
            if (o16) gemm_mfma<0, 1, 1><<<grid, 256, 0, stream>>>(A, BT, bias, C, M, Nn, K);
            else     gemm_mfma<0, 1, 0><<<grid, 256, 0, stream>>>(A, BT, bias, C, M, Nn, K);
        } else if (act) {
            gemm_mfma<1, 0, 1><<<grid, 256, 0, stream>>>(A, BT, bias, C, M, Nn, K);
        } else {
            if (o16) gemm_mfma<0, 0, 1><<<grid, 256, 0, stream>>>(A, BT, bias, C, M, Nn, K);
            else     gemm_mfma<0, 0, 0><<<grid, 256, 0, stream>>>(A, BT, bias, C, M, Nn, K);
        }
    };

    // ---- Embedding: H0 = x @ emb_w + emb_b (fp32 out) ----
    gemm(x, wt_emb, emb_b, H0, n, HDIM, IN_DIM, 0, 0, 0);

    // ---- 3 GATv2 + FFN layers ----
    for (int i = 0; i < 3; i++) {
        int concat = (i < 2);
        gemm(H0, wt_ll + (size_t)i * HDIM * HH, nullptr, XL, n, HH, HDIM, 0, 0, 1);
        gemm(H0, wt_lr + (size_t)i * HDIM * HH, nullptr, XR, n, HH, HDIM, 0, 0, 1);
        gat_edge_kernel<<<(n + 3) / 4, 256, 0, stream>>>(
            XL, XR, row_ptr, csr_src, csr_ea,
            lin_edge + (size_t)i * 2 * HH, attw + (size_t)i * HH,
            concat ? (cb01 + (size_t)i * HH) : cb2,
            XR, H1, n, concat);
        if (concat)
            gemm(XR, wt_proj + (size_t)i * HH * HDIM, proj_b + (size_t)i * HDIM,
                 H1, n, HDIM, HH, 0, 1, 0);
        ln_res_kernel<<<(n + 3) / 4, 256, 0, stream>>>(
            H1, H0, n1g + (size_t)i * HDIM, n1b + (size_t)i * HDIM, H1, n);
        gemm(H1, wt_f1 + (size_t)i * HDIM * FFH, fb1 + (size_t)i * FFH, MID, n, FFH, HDIM, 1, 0, 1);
        gemm(MID, wt_f2 + (size_t)i * FFH * HDIM, fb2 + (size_t)i * HDIM, H0, n, HDIM, FFH, 0, 1, 0);
        float* lnout = (i == 2) ? out : H0;
        ln_res_kernel<<<(n + 3) / 4, 256, 0, stream>>>(
            H0, H1, n2g + (size_t)i * HDIM, n2b + (size_t)i * HDIM, lnout, n);
    }
}

// Round 5
// 705.376 us; speedup vs baseline: 1.7762x; 1.1165x over previous
//
#include <hip/hip_runtime.h>
#include <math.h>

#define IN_DIM 16
#define HDIM   128
#define HEADS  4
#define HH     512   // HEADS*HDIM
#define FFH    256   // 2*HDIM
#define NEG_SLOPE 0.2f

typedef _Float16 half8 __attribute__((ext_vector_type(8)));
typedef _Float16 h8 __attribute__((ext_vector_type(8)));
typedef _Float16 h4 __attribute__((ext_vector_type(4)));
typedef _Float16 h2 __attribute__((ext_vector_type(2)));
typedef float f32x4 __attribute__((ext_vector_type(4)));

struct __align__(8) Edge { int src; _Float16 ea0, ea1; };

static __device__ inline float hsum8(h8 v) {
    h4 a = __builtin_shufflevector(v, v, 0, 1, 2, 3) +
           __builtin_shufflevector(v, v, 4, 5, 6, 7);
    h2 b = __builtin_shufflevector(a, a, 0, 1) +
           __builtin_shufflevector(a, a, 2, 3);
    return (float)b[0] + (float)b[1];
}

// ---------------------------------------------------------------------------
// x pad: xh[n][64] = f16(x[n][16]) zero-padded
// ---------------------------------------------------------------------------
__global__ void xpad_kernel(const float* __restrict__ x, _Float16* __restrict__ xh, int n) {
    int idx = blockIdx.x * 256 + threadIdx.x;
    if (idx >= n * 64) return;
    int r = idx >> 6, k = idx & 63;
    xh[idx] = (k < IN_DIM) ? (_Float16)x[r * IN_DIM + k] : (_Float16)0.0f;
}

// ---------------------------------------------------------------------------
// Weight convert+transpose+K-pad: W[Ksrc][N] fp32 -> WT[N][Kd] f16 (zero pad)
// ---------------------------------------------------------------------------
struct WDesc { const float* src; _Float16* dst; int Ksrc; int lgKd; int lgN; };
struct WDescs { WDesc d[15]; };
__global__ void wconv_kernel(WDescs ds) {
    WDesc w = ds.d[blockIdx.y];
    int Kd = 1 << w.lgKd;
    int total = 1 << (w.lgKd + w.lgN);
    for (int idx = blockIdx.x * 256 + threadIdx.x; idx < total; idx += gridDim.x * 256) {
        int n2 = idx >> w.lgKd, k = idx & (Kd - 1);
        w.dst[idx] = (k < w.Ksrc) ? (_Float16)w.src[(k << w.lgN) + n2] : (_Float16)0.0f;
    }
}

// ---------------------------------------------------------------------------
// Preprocess: degree + edge_attr sums (self-loop fill_value='mean')
// ---------------------------------------------------------------------------
__global__ void deg_kernel(const int* __restrict__ ei, const float* __restrict__ eattr,
                           float* deg, float* asum, int E) {
    int e = blockIdx.x * blockDim.x + threadIdx.x;
    if (e >= E) return;
    int d = ei[E + e];
    atomicAdd(&deg[d], 1.0f);
    atomicAdd(&asum[2 * d], eattr[2 * e]);
    atomicAdd(&asum[2 * d + 1], eattr[2 * e + 1]);
}

__global__ void scan_kernel(const float* __restrict__ deg, int* row_ptr, int* cur, int n) {
    __shared__ int sums[1024];
    __shared__ int offs[1025];
    int tid = threadIdx.x;
    int per = (n + 1023) / 1024;
    int s0 = tid * per;
    int s1 = s0 + per; if (s1 > n) s1 = n;
    int s = 0;
    for (int i = s0; i < s1; i++) s += (int)deg[i] + 1;
    sums[tid] = s;
    __syncthreads();
    if (tid == 0) {
        int run = 0;
        for (int i = 0; i < 1024; i++) { offs[i] = run; run += sums[i]; }
        offs[1024] = run;
    }
    __syncthreads();
    int run = offs[tid];
    for (int i = s0; i < s1; i++) {
        row_ptr[i] = run; cur[i] = run;
        run += (int)deg[i] + 1;
    }
    if (tid == 0) row_ptr[n] = offs[1024];
}

__global__ void scatter_kernel(const int* __restrict__ ei, const float* __restrict__ eattr,
                               const float* __restrict__ deg, const float* __restrict__ asum,
                               int* cur, Edge* csr, int E, int n) {
    int i = blockIdx.x * blockDim.x + threadIdx.x;
    if (i >= E + n) return;
    Edge ed;
    int pos;
    if (i < E) {
        int d = ei[E + i];
        pos = atomicAdd(&cur[d], 1);
        ed.src = ei[i];
        ed.ea0 = (_Float16)eattr[2 * i];
        ed.ea1 = (_Float16)eattr[2 * i + 1];
    } else {
        int nd = i - E;
        float dv = fmaxf(deg[nd], 1.0f);
        pos = atomicAdd(&cur[nd], 1);
        ed.src = nd;
        ed.ea0 = (_Float16)(asum[2 * nd] / dv);
        ed.ea1 = (_Float16)(asum[2 * nd + 1] / dv);
    }
    csr[pos] = ed;
}

// ---------------------------------------------------------------------------
// MFMA f16 GEMM: C[M,N] = A[M,K](f16, row-stride lda) @ BT[N][K](f16)
// (+bias)(+GELU). Block tile BMx128, BK=64, 4 waves 2x2, wave (BM/2)x64.
// Requires N%128==0, K%64==0. OUTMODE: 0=f32, 1=f16, 2=both.
// ---------------------------------------------------------------------------
template <int ACT, int OUTMODE, int BM>
__global__ __launch_bounds__(256) void gemm_mfma(const _Float16* __restrict__ A, int lda,
                                                 const _Float16* __restrict__ BT,
                                                 const float* __restrict__ bias,
                                                 float* __restrict__ C32,
                                                 _Float16* __restrict__ C16,
                                                 int M, int N, int K) {
    const int BK = 64, PAD = 8, NI = BM / 32;
    __shared__ _Float16 As[BM][BK + PAD];
    __shared__ _Float16 Bs[128][BK + PAD];
    int tid = threadIdx.x;
    int wave = tid >> 6, lane = tid & 63;
    int quad = lane >> 4, l16 = lane & 15;
    int wrow = (wave >> 1) * (16 * NI);
    int wcol = (wave & 1) * 64;
    int mBase = blockIdx.y * BM;
    int n0 = blockIdx.x * 128;

    f32x4 acc[NI][4] = {};

    for (int k0 = 0; k0 < K; k0 += BK) {
#pragma unroll
        for (int t = 0; t < BM / 32; t++) {
            int idx = tid + t * 256;
            int r = idx >> 3, kb = (idx & 7) * 8;
            half8 hv = {};
            int grow = mBase + r;
            if (grow < M) hv = *(const half8*)(A + (size_t)grow * lda + k0 + kb);
            *(half8*)&As[r][kb] = hv;
        }
#pragma unroll
        for (int t = 0; t < 4; t++) {
            int idx = tid + t * 256;
            int r = idx >> 3, kb = (idx & 7) * 8;
            *(half8*)&Bs[r][kb] = *(const half8*)(BT + (size_t)(n0 + r) * K + k0 + kb);
        }
        __syncthreads();
#pragma unroll
        for (int kc = 0; kc < 2; kc++) {
            half8 a[NI], b[4];
#pragma unroll
            for (int i = 0; i < NI; i++)
                a[i] = *(const half8*)&As[wrow + i * 16 + l16][kc * 32 + quad * 8];
#pragma unroll
            for (int j = 0; j < 4; j++)
                b[j] = *(const half8*)&Bs[wcol + j * 16 + l16][kc * 32 + quad * 8];
#pragma unroll
            for (int i = 0; i < NI; i++)
#pragma unroll
                for (int j = 0; j < 4; j++)
                    acc[i][j] = __builtin_amdgcn_mfma_f32_16x16x32_f16(a[i], b[j], acc[i][j], 0, 0, 0);
        }
        __syncthreads();
    }

#pragma unroll
    for (int i = 0; i < NI; i++) {
#pragma unroll
        for (int r = 0; r < 4; r++) {
            int row = mBase + wrow + i * 16 + quad * 4 + r;
            if (row >= M) continue;
#pragma unroll
            for (int j = 0; j < 4; j++) {
                int col = n0 + wcol + j * 16 + l16;
                float v = acc[i][j][r] + (bias ? bias[col] : 0.0f);
                if (ACT == 1) v = 0.5f * v * (1.0f + erff(v * 0.70710678118654752f));
                if (OUTMODE == 0 || OUTMODE == 2)
                    C32[(size_t)row * N + col] = v;
                if (OUTMODE == 1 || OUTMODE == 2)
                    C16[(size_t)row * N + col] = (_Float16)v;
            }
        }
    }
}

// ---------------------------------------------------------------------------
// GATv2 attention + aggregation, packed-f16 math (native _Float16 vectors),
// one wave per dst node, online softmax, 2-edge unroll. XLR: [n][1024] f16
// (XL cols 0..511, XR 512..1023). Concat: writes f16 back into XR half.
// Non-concat: head-mean fp32 to OUT32.
// ---------------------------------------------------------------------------
__global__ __launch_bounds__(256) void gat_edge_kernel(
    const _Float16* __restrict__ XLR,
    const int* __restrict__ row_ptr, const Edge* __restrict__ csr,
    const float* __restrict__ We,    // [2,512]
    const float* __restrict__ attW,  // [512]
    const float* __restrict__ cbias, // [512] or [128]
    _Float16* __restrict__ OUT16, float* __restrict__ OUT32, int n, int concat) {
    int tid = threadIdx.x;
    int wave = tid >> 6, lane = tid & 63;
    int node = blockIdx.x * 4 + wave;
    if (node >= n) return;
    int c0 = lane * 8;

    h8 xr8 = *(const h8*)(XLR + (size_t)node * 1024 + 512 + c0);
    h8 w08, w18, att8;
#pragma unroll
    for (int k = 0; k < 8; k++) {
        w08[k] = (_Float16)We[c0 + k];
        w18[k] = (_Float16)We[HH + c0 + k];
        att8[k] = (_Float16)attW[c0 + k];
    }
    const _Float16 slope = (_Float16)NEG_SLOPE;

    h8 acc2 = (h8)(_Float16)0.0f;
    float m = -INFINITY, l = 0.0f;
    int beg = row_ptr[node], end = row_ptr[node + 1];
    int j = beg;
    for (; j + 1 < end; j += 2) {
        Edge e0 = csr[j], e1 = csr[j + 1];
        h8 x0 = *(const h8*)(XLR + (size_t)e0.src * 1024 + c0);
        h8 x1 = *(const h8*)(XLR + (size_t)e1.src * 1024 + c0);
        h8 v0 = x0 + (xr8 + w08 * e0.ea0 + w18 * e0.ea1);
        h8 v1 = x1 + (xr8 + w08 * e1.ea0 + w18 * e1.ea1);
        v0 = __builtin_elementwise_max(v0, v0 * slope);
        v1 = __builtin_elementwise_max(v1, v1 * slope);
        float p0 = hsum8(v0 * att8);
        float p1 = hsum8(v1 * att8);
        p0 += __shfl_xor(p0, 1); p1 += __shfl_xor(p1, 1);
        p0 += __shfl_xor(p0, 2); p1 += __shfl_xor(p1, 2);
        p0 += __shfl_xor(p0, 4); p1 += __shfl_xor(p1, 4);
        p0 += __shfl_xor(p0, 8); p1 += __shfl_xor(p1, 8);
        float mnew = fmaxf(m, fmaxf(p0, p1));
        float sc = __expf(m - mnew);
        float e0f = __expf(p0 - mnew);
        float e1f = __expf(p1 - mnew);
        l = l * sc + e0f + e1f;
        acc2 = acc2 * (_Float16)sc + x0 * (_Float16)e0f + x1 * (_Float16)e1f;
        m = mnew;
    }
    if (j < end) {
        Edge e0 = csr[j];
        h8 x0 = *(const h8*)(XLR + (size_t)e0.src * 1024 + c0);
        h8 v0 = x0 + (xr8 + w08 * e0.ea0 + w18 * e0.ea1);
        v0 = __builtin_elementwise_max(v0, v0 * slope);
        float p0 = hsum8(v0 * att8);
        p0 += __shfl_xor(p0, 1);
        p0 += __shfl_xor(p0, 2);
        p0 += __shfl_xor(p0, 4);
        p0 += __shfl_xor(p0, 8);
        float mnew = fmaxf(m, p0);
        float sc = __expf(m - mnew);
        float e0f = __expf(p0 - mnew);
        l = l * sc + e0f;
        acc2 = acc2 * (_Float16)sc + x0 * (_Float16)e0f;
        m = mnew;
    }
    float invf = 1.0f / (l + 1e-16f);
    if (concat) {
        h8 o = acc2 * (_Float16)invf;
#pragma unroll
        for (int k = 0; k < 8; k++) o[k] = o[k] + (_Float16)cbias[c0 + k];
        *(h8*)(OUT16 + (size_t)node * 1024 + c0) = o;
    } else {
        float o8[8];
#pragma unroll
        for (int k = 0; k < 8; k++) {
            float a = (float)acc2[k] * invf;
            a += __shfl_xor(a, 16);
            a += __shfl_xor(a, 32);
            o8[k] = a;
        }
        if (lane < 16) {
#pragma unroll
            for (int k = 0; k < 8; k++)
                OUT32[(size_t)node * HDIM + c0 + k] = o8[k] * 0.25f + cbias[c0 + k];
        }
    }
}

// ---------------------------------------------------------------------------
// LayerNorm over last dim (128) of (X + R); dual write fp32 (+f16 if OUT16).
// OUT32 may alias X (same-thread read-before-write).
// ---------------------------------------------------------------------------
__global__ __launch_bounds__(256) void ln_res_kernel(const float* X, const float* R,
                                                     const float* __restrict__ g,
                                                     const float* __restrict__ b,
                                                     float* OUT32, _Float16* OUT16, int n) {
    int wave = threadIdx.x >> 6, lane = threadIdx.x & 63;
    int row = blockIdx.x * 4 + wave;
    if (row >= n) return;
    int c = lane * 2;
    size_t base = (size_t)row * HDIM;
    float x0 = X[base + c] + R[base + c];
    float x1 = X[base + c + 1] + R[base + c + 1];
    float s = x0 + x1;
#pragma unroll
    for (int off = 1; off < 64; off <<= 1) s += __shfl_xor(s, off);
    float mu = s * (1.0f / HDIM);
    float d0 = x0 - mu, d1 = x1 - mu;
    float vs = d0 * d0 + d1 * d1;
#pragma unroll
    for (int off = 1; off < 64; off <<= 1) vs += __shfl_xor(vs, off);
    float invstd = rsqrtf(vs * (1.0f / HDIM) + 1e-5f);
    float o0 = d0 * invstd * g[c] + b[c];
    float o1 = d1 * invstd * g[c + 1] + b[c + 1];
    OUT32[base + c] = o0;
    OUT32[base + c + 1] = o1;
    if (OUT16) {
        OUT16[base + c] = (_Float16)o0;
        OUT16[base + c + 1] = (_Float16)o1;
    }
}

// ---------------------------------------------------------------------------
extern "C" void kernel_launch(void* const* d_in, const int* in_sizes, int n_in,
                              void* d_out, int out_size, void* d_ws, size_t ws_size,
                              hipStream_t stream) {
    const float* x        = (const float*)d_in[0];
    const int*   ei       = (const int*)d_in[1];
    const float* eattr    = (const float*)d_in[2];
    const float* emb_w    = (const float*)d_in[3];
    const float* emb_b    = (const float*)d_in[4];
    const float* lin_l    = (const float*)d_in[5];
    const float* lin_r    = (const float*)d_in[6];
    const float* lin_edge = (const float*)d_in[7];
    const float* attw     = (const float*)d_in[8];
    const float* cb01     = (const float*)d_in[9];
    const float* cb2      = (const float*)d_in[10];
    const float* proj_w   = (const float*)d_in[11];
    const float* proj_b   = (const float*)d_in[12];
    const float* n1g      = (const float*)d_in[13];
    const float* n1b      = (const float*)d_in[14];
    const float* n2g      = (const float*)d_in[15];
    const float* n2b      = (const float*)d_in[16];
    const float* fw1      = (const float*)d_in[17];
    const float* fb1      = (const float*)d_in[18];
    const float* fw2      = (const float*)d_in[19];
    const float* fb2      = (const float*)d_in[20];
    float* out = (float*)d_out;

    const int n = in_sizes[0] / IN_DIM;   // 20000
    const int E = in_sizes[2] / 2;        // 320000
    const int EP = E + n;

    size_t off = 0;
    auto alloc = [&](size_t bytes) {
        void* p = (char*)d_ws + off;
        off += (bytes + 255) & ~(size_t)255;
        return p;
    };
    float* deg     = (float*)alloc((size_t)n * 4);
    float* asum    = (float*)alloc((size_t)2 * n * 4);
    int*   row_ptr = (int*)alloc((size_t)(n + 1) * 4);
    int*   cur     = (int*)alloc((size_t)n * 4);
    Edge*  csr     = (Edge*)alloc((size_t)EP * 8);
    float* H0      = (float*)alloc((size_t)n * HDIM * 4);
    float* H1      = (float*)alloc((size_t)n * HDIM * 4);
    _Float16* H0h  = (_Float16*)alloc((size_t)n * HDIM * 2);
    _Float16* H1h  = (_Float16*)alloc((size_t)n * HDIM * 2);
    _Float16* MID  = (_Float16*)alloc((size_t)n * FFH * 2);
    _Float16* XLR  = (_Float16*)alloc((size_t)n * 1024 * 2);
    _Float16* xh   = (_Float16*)alloc((size_t)n * 64 * 2);
    _Float16* wt_emb  = (_Float16*)alloc((size_t)HDIM * 64 * 2);
    _Float16* wt_llr  = (_Float16*)alloc((size_t)3 * 1024 * HDIM * 2);
    _Float16* wt_proj = (_Float16*)alloc((size_t)2 * HDIM * HH * 2);
    _Float16* wt_f1   = (_Float16*)alloc((size_t)3 * FFH * HDIM * 2);
    _Float16* wt_f2   = (_Float16*)alloc((size_t)3 * HDIM * FFH * 2);
    (void)ws_size;

    // ---- input prep ----
    xpad_kernel<<<(n * 64 + 255) / 256, 256, 0, stream>>>(x, xh, n);
    WDescs ds;
    int di = 0;
    ds.d[di++] = {emb_w, wt_emb, IN_DIM, 6, 7};
    for (int i = 0; i < 3; i++) {
        ds.d[di++] = {lin_l + (size_t)i * HDIM * HH, wt_llr + (size_t)i * 1024 * HDIM, HDIM, 7, 9};
        ds.d[di++] = {lin_r + (size_t)i * HDIM * HH, wt_llr + (size_t)i * 1024 * HDIM + (size_t)512 * HDIM, HDIM, 7, 9};
    }
    for (int i = 0; i < 2; i++)
        ds.d[di++] = {proj_w + (size_t)i * HH * HDIM, wt_proj + (size_t)i * HDIM * HH, HH, 9, 7};
    for (int i = 0; i < 3; i++)
        ds.d[di++] = {fw1 + (size_t)i * HDIM * FFH, wt_f1 + (size_t)i * FFH * HDIM, HDIM, 7, 8};
    for (int i = 0; i < 3; i++)
        ds.d[di++] = {fw2 + (size_t)i * FFH * HDIM, wt_f2 + (size_t)i * HDIM * FFH, FFH, 8, 7};
    wconv_kernel<<<dim3(32, 15), 256, 0, stream>>>(ds);

    // ---- CSR build ----
    (void)hipMemsetAsync(deg, 0, (size_t)n * 4, stream);
    (void)hipMemsetAsync(asum, 0, (size_t)2 * n * 4, stream);
    deg_kernel<<<(E + 255) / 256, 256, 0, stream>>>(ei, eattr, deg, asum, E);
    scan_kernel<<<1, 1024, 0, stream>>>(deg, row_ptr, cur, n);
    scatter_kernel<<<(EP + 255) / 256, 256, 0, stream>>>(ei, eattr, deg, asum, cur, csr, E, n);

    // ---- Embedding: H0(+H0h) = xh @ wt_emb + emb_b ----
    gemm_mfma<0, 2, 128><<<dim3(1, (n + 127) / 128), 256, 0, stream>>>(
        xh, 64, wt_emb, emb_b, H0, H0h, n, HDIM, 64);

    // ---- 3 GATv2 + FFN layers ----
    for (int i = 0; i < 3; i++) {
        int concat = (i < 2);
        // fused lin_l|lin_r: XLR[n][1024]
        gemm_mfma<0, 1, 128><<<dim3(8, (n + 127) / 128), 256, 0, stream>>>(
            H0h, HDIM, wt_llr + (size_t)i * 1024 * HDIM, nullptr, nullptr, XLR, n, 1024, HDIM);
        gat_edge_kernel<<<(n + 3) / 4, 256, 0, stream>>>(
            XLR, row_ptr, csr,
            lin_edge + (size_t)i * 2 * HH, attw + (size_t)i * HH,
            concat ? (cb01 + (size_t)i * HH) : cb2,
            XLR + 512, H1, n, concat);
        if (concat)
            gemm_mfma<0, 0, 64><<<dim3(1, (n + 63) / 64), 256, 0, stream>>>(
                XLR + 512, 1024, wt_proj + (size_t)i * HDIM * HH,
                proj_b + (size_t)i * HDIM, H1, nullptr, n, HDIM, HH);
        ln_res_kernel<<<(n + 3) / 4, 256, 0, stream>>>(
            H1, H0, n1g + (size_t)i * HDIM, n1b + (size_t)i * HDIM, H1, H1h, n);
        gemm_mfma<1, 1, 128><<<dim3(2, (n + 127) / 128), 256, 0, stream>>>(
            H1h, HDIM, wt_f1 + (size_t)i * FFH * HDIM, fb1 + (size_t)i * FFH,
            nullptr, MID, n, FFH, HDIM);
        gemm_mfma<0, 0, 64><<<dim3(1, (n + 63) / 64), 256, 0, stream>>>(
            MID, FFH, wt_f2 + (size_t)i * HDIM * FFH, fb2 + (size_t)i * HDIM,
            H0, nullptr, n, HDIM, FFH);
        float* lnout = (i == 2) ? out : H0;
        _Float16* lnout16 = (i == 2) ? nullptr : H0h;
        ln_res_kernel<<<(n + 3) / 4, 256, 0, stream>>>(
            H0, H1, n2g + (size_t)i * HDIM, n2b + (size_t)i * HDIM, lnout, lnout16, n);
    }
}